// Round 1
// baseline (2814.532 us; speedup 1.0000x reference)
//
#include <hip/hip_runtime.h>
#include <math.h>

#define DEVFN static __device__ __forceinline__

constexpr int Bn = 1024, Dn = 128, Wn = 512, Tn = 8;
constexpr int NSTEP = 48;
constexpr int RPB = 4;            // batch rows per block
constexpr int NBLK = Bn / RPB;    // 256 blocks
constexpr int NTHR = 256;
constexpr int BD = Bn * Dn;

// workspace byte offsets
constexpr size_t OFF_SLOTS = 0;                            // 48 doubles
constexpr size_t OFF_STATE = 512;                          // 2 x 64B state slots
constexpr size_t OFF_W0T   = 1024;                         // [Dn][Wn] f32
constexpr size_t OFF_W1T   = OFF_W0T + (size_t)Dn*Wn*4;    // [Wn][Wn] f32
constexpr size_t OFF_W2T   = OFF_W1T + (size_t)Wn*Wn*4;    // [Wn][Dn] f32
constexpr size_t OFF_Y     = OFF_W2T + (size_t)Wn*Dn*4;    // 2 x [Bn][Dn] f32
constexpr size_t OFF_K     = OFF_Y   + (size_t)2*BD*4;     // 2 x [Bn][Dn] f32

struct OdeState { int si; int cur; float t; float dt; };

// Tsit5 tableau (float)
constexpr float A21f = 0.161f;
constexpr float A31f = -0.008480655492356989f, A32f = 0.335480655492357f;
constexpr float A41f = 2.8971530571054935f, A42f = -6.359448489975075f, A43f = 4.3622954328695815f;
constexpr float A51f = 5.325864828439257f, A52f = -11.748883564062828f, A53f = 7.4955393428898365f, A54f = -0.09249506636175525f;
constexpr float A61f = 5.86145544294642f, A62f = -12.92096931784711f, A63f = 8.159367898576159f, A64f = -0.071584973281401f, A65f = -0.028269050394068383f;
constexpr float B1f = 0.09646076681806523f, B2f = 0.01f, B3f = 0.4798896504144996f, B4f = 1.379008574103742f, B5f = -3.290069515436081f, B6f = 2.324710524099774f;
constexpr float E1f = -0.00178001105222577714f, E2f = -0.0008164344596567469f, E3f = 0.007880878010261995f, E4f = -0.1447110071732629f, E5f = 0.5823571654525552f, E6f = -0.45808210592918697f, E7f = 0.015151515151515152f;

DEVFN float softplusf(float x) {
  // jax.nn.softplus == logaddexp(x, 0) == max(x,0) + log1p(exp(-|x|))
  return fmaxf(x, 0.f) + log1pf(expf(-fabsf(x)));
}

// f(z) for this block's RPB rows. zl: [RPB][Dn] in LDS. Writes kout [RPB][Dn] (LDS)
// and optionally kglob (global rows). Internally syncs between layers; caller must
// sync before reading kout from a different thread mapping.
DEVFN void eval_f(const float* __restrict__ zl, float* __restrict__ h1l,
                  float* __restrict__ h2l, float* __restrict__ kout,
                  float* __restrict__ kglob,
                  const float* __restrict__ W0T, const float* __restrict__ W1T,
                  const float* __restrict__ W2T,
                  const float* __restrict__ b0, const float* __restrict__ b1,
                  const float* __restrict__ b2, int tid)
{
  // layer 1: Dn -> Wn, softplus
  {
    const int o = tid * 2;
    float acc[RPB][2];
#pragma unroll
    for (int r = 0; r < RPB; ++r) { acc[r][0] = 0.f; acc[r][1] = 0.f; }
    for (int i = 0; i < Dn; i += 4) {
      float zv[RPB][4];
#pragma unroll
      for (int r = 0; r < RPB; ++r) {
        float4 t4 = *(const float4*)&zl[r*Dn + i];
        zv[r][0] = t4.x; zv[r][1] = t4.y; zv[r][2] = t4.z; zv[r][3] = t4.w;
      }
#pragma unroll
      for (int ii = 0; ii < 4; ++ii) {
        const float2 w = *(const float2*)&W0T[(size_t)(i+ii)*Wn + o];
#pragma unroll
        for (int r = 0; r < RPB; ++r) {
          acc[r][0] = fmaf(zv[r][ii], w.x, acc[r][0]);
          acc[r][1] = fmaf(zv[r][ii], w.y, acc[r][1]);
        }
      }
    }
    const float bo0 = b0[o], bo1 = b0[o+1];
#pragma unroll
    for (int r = 0; r < RPB; ++r) {
      h1l[r*Wn + o]     = softplusf(acc[r][0] + bo0);
      h1l[r*Wn + o + 1] = softplusf(acc[r][1] + bo1);
    }
  }
  __syncthreads();
  // layer 2: Wn -> Wn, softplus
  {
    const int o = tid * 2;
    float acc[RPB][2];
#pragma unroll
    for (int r = 0; r < RPB; ++r) { acc[r][0] = 0.f; acc[r][1] = 0.f; }
    for (int i = 0; i < Wn; i += 4) {
      float zv[RPB][4];
#pragma unroll
      for (int r = 0; r < RPB; ++r) {
        float4 t4 = *(const float4*)&h1l[r*Wn + i];
        zv[r][0] = t4.x; zv[r][1] = t4.y; zv[r][2] = t4.z; zv[r][3] = t4.w;
      }
#pragma unroll
      for (int ii = 0; ii < 4; ++ii) {
        const float2 w = *(const float2*)&W1T[(size_t)(i+ii)*Wn + o];
#pragma unroll
        for (int r = 0; r < RPB; ++r) {
          acc[r][0] = fmaf(zv[r][ii], w.x, acc[r][0]);
          acc[r][1] = fmaf(zv[r][ii], w.y, acc[r][1]);
        }
      }
    }
    const float bo0 = b1[o], bo1 = b1[o+1];
#pragma unroll
    for (int r = 0; r < RPB; ++r) {
      h2l[r*Wn + o]     = softplusf(acc[r][0] + bo0);
      h2l[r*Wn + o + 1] = softplusf(acc[r][1] + bo1);
    }
  }
  __syncthreads();
  // layer 3: Wn -> Dn (no activation)
  {
    const int g  = tid >> 6;          // row (one wave per row)
    const int oc = (tid & 63) * 2;    // col pair
    float a0 = 0.f, a1 = 0.f;
    for (int i = 0; i < Wn; i += 4) {
      float hv[4];
      float4 t4 = *(const float4*)&h2l[g*Wn + i];
      hv[0] = t4.x; hv[1] = t4.y; hv[2] = t4.z; hv[3] = t4.w;
#pragma unroll
      for (int ii = 0; ii < 4; ++ii) {
        const float2 w = *(const float2*)&W2T[(size_t)(i+ii)*Dn + oc];
        a0 = fmaf(hv[ii], w.x, a0);
        a1 = fmaf(hv[ii], w.y, a1);
      }
    }
    a0 += b2[oc]; a1 += b2[oc+1];
    kout[g*Dn + oc]     = a0;
    kout[g*Dn + oc + 1] = a1;
    if (kglob) { kglob[g*Dn + oc] = a0; kglob[g*Dn + oc + 1] = a1; }
  }
}

template<int N>
DEVFN void combine(float* __restrict__ zl, const float* __restrict__ yl, float h,
                   const float* c, const float (*kkl)[RPB*Dn],
                   float* __restrict__ yglob, int tid)
{
  for (int e = tid; e < RPB*Dn; e += NTHR) {
    float a = c[0] * kkl[0][e];
#pragma unroll
    for (int l = 1; l < N; ++l) a = fmaf(c[l], kkl[l][e], a);
    const float v = fmaf(h, a, yl[e]);
    zl[e] = v;
    if (yglob) yglob[e] = v;
  }
}

__global__ __launch_bounds__(256) void ode_init(
    const float* __restrict__ ts, const float* __restrict__ y0,
    const float* __restrict__ W0, const float* __restrict__ W1,
    const float* __restrict__ W2, char* __restrict__ ws, float* __restrict__ out)
{
  const int idx = blockIdx.x * blockDim.x + threadIdx.x;
  float* W0T = (float*)(ws + OFF_W0T);
  float* W1T = (float*)(ws + OFF_W1T);
  float* W2T = (float*)(ws + OFF_W2T);
  float* y0b = (float*)(ws + OFF_Y);
  double* slots = (double*)(ws + OFF_SLOTS);

  if (idx < Tn*BD) out[idx] = (idx < BD) ? y0[idx] : 0.f;  // ys[0]=y0, rest zero
  if (idx < BD) y0b[idx] = y0[idx];
  if (idx < Dn*Wn) { const int i = idx >> 9, o = idx & (Wn-1); W0T[idx] = W0[o*Dn + i]; }
  if (idx < Wn*Wn) { const int i = idx >> 9, o = idx & (Wn-1); W1T[idx] = W1[o*Wn + i]; }
  if (idx < Wn*Dn) { const int i = idx >> 7, o = idx & (Dn-1); W2T[idx] = W2[o*Wn + i]; }
  if (idx < NSTEP) slots[idx] = 0.0;
  if (idx == 0) {
    OdeState s0; s0.si = 1; s0.cur = 0; s0.t = 0.f; s0.dt = ts[1] - ts[0];
    *(OdeState*)(ws + OFF_STATE)      = s0;
    *(OdeState*)(ws + OFF_STATE + 64) = s0;
  }
}

// Kernel s: phase B of step s-1 (finalize from reduced enorm), then phase A of
// step s (stages k2..k7 via FSAL, error partial sums). s==NSTEP is finalize-only.
__global__ __launch_bounds__(NTHR) void ode_step(
    int s, const float* __restrict__ ts,
    const float* __restrict__ b0, const float* __restrict__ b1,
    const float* __restrict__ b2,
    char* __restrict__ ws, float* __restrict__ out)
{
  const float* W0T = (const float*)(ws + OFF_W0T);
  const float* W1T = (const float*)(ws + OFF_W1T);
  const float* W2T = (const float*)(ws + OFF_W2T);
  float* ybuf = (float*)(ws + OFF_Y);
  float* kbuf = (float*)(ws + OFF_K);
  double* slots = (double*)(ws + OFF_SLOTS);

  __shared__ __align__(16) float zl[RPB*Dn];
  __shared__ __align__(16) float yl[RPB*Dn];
  __shared__ __align__(16) float h1l[RPB*Wn];
  __shared__ __align__(16) float h2l[RPB*Wn];
  __shared__ __align__(16) float kkl[7][RPB*Dn];
  __shared__ float wred[NTHR/64];

  const int tid  = threadIdx.x;
  const int row0 = blockIdx.x * RPB;

  OdeState st = *(const OdeState*)(ws + OFF_STATE + 64*(s & 1));

  if (s > 0) {
    // ---- phase B of step s-1: every block recomputes identically ----
    const bool donep = st.si >= Tn;
    const int sic = min(st.si, Tn - 1);
    const float tns = ts[sic];
    const float h = donep ? 0.f : fmaxf(fminf(st.dt, tns - st.t), 0.f);
    const float enorm = (float)sqrt(slots[s-1] / (double)BD);
    const bool accept = (enorm <= 1.f) && !donep;
    const float tnew = st.t + h;
    const bool hit = accept && (tnew >= tns - 1e-6f);
    if (accept) { st.cur ^= 1; st.t = tnew; }
    if (hit) {
      const float* yn = ybuf + (size_t)st.cur*BD + row0*Dn;
      float* op = out + (size_t)sic*BD + row0*Dn;
      for (int e = tid; e < RPB*Dn; e += NTHR) op[e] = yn[e];
      st.si += 1;
    }
    if (!donep) {
      const float safe_e = (enorm > 0.f) ? enorm : 1.f;
      const float factor = (enorm > 0.f)
          ? fminf(fmaxf(0.9f * powf(safe_e, -0.2f), 0.2f), 10.f) : 10.f;
      st.dt *= factor;
    }
    if (blockIdx.x == 0 && tid == 0)
      *(OdeState*)(ws + OFF_STATE + 64*((s+1) & 1)) = st;   // publish S_s
  }

  if (st.si >= Tn || s >= NSTEP) return;   // done (or finalize-only launch)

  // ---- phase A of step s ----
  const int sic = min(st.si, Tn - 1);
  const float tns = ts[sic];
  const float h = fmaxf(fminf(st.dt, tns - st.t), 0.f);

  const float* yg = ybuf + (size_t)st.cur*BD + row0*Dn;
  for (int e = tid; e < RPB*Dn; e += NTHR) yl[e] = yg[e];

  if (s == 0) {                 // bootstrap k1 = f(y0)
    for (int e = tid; e < RPB*Dn; e += NTHR) zl[e] = yg[e];
    __syncthreads();
    eval_f(zl, h1l, h2l, kkl[0], kbuf + (size_t)st.cur*BD + row0*Dn,
           W0T, W1T, W2T, b0, b1, b2, tid);
  } else {                      // FSAL: k1 already in kbuf[cur]
    const float* kg = kbuf + (size_t)st.cur*BD + row0*Dn;
    for (int e = tid; e < RPB*Dn; e += NTHR) kkl[0][e] = kg[e];
  }
  __syncthreads();

  { const float c[1] = {A21f};
    combine<1>(zl, yl, h, c, kkl, nullptr, tid); }
  __syncthreads();
  eval_f(zl, h1l, h2l, kkl[1], nullptr, W0T, W1T, W2T, b0, b1, b2, tid);
  __syncthreads();

  { const float c[2] = {A31f, A32f};
    combine<2>(zl, yl, h, c, kkl, nullptr, tid); }
  __syncthreads();
  eval_f(zl, h1l, h2l, kkl[2], nullptr, W0T, W1T, W2T, b0, b1, b2, tid);
  __syncthreads();

  { const float c[3] = {A41f, A42f, A43f};
    combine<3>(zl, yl, h, c, kkl, nullptr, tid); }
  __syncthreads();
  eval_f(zl, h1l, h2l, kkl[3], nullptr, W0T, W1T, W2T, b0, b1, b2, tid);
  __syncthreads();

  { const float c[4] = {A51f, A52f, A53f, A54f};
    combine<4>(zl, yl, h, c, kkl, nullptr, tid); }
  __syncthreads();
  eval_f(zl, h1l, h2l, kkl[4], nullptr, W0T, W1T, W2T, b0, b1, b2, tid);
  __syncthreads();

  { const float c[5] = {A61f, A62f, A63f, A64f, A65f};
    combine<5>(zl, yl, h, c, kkl, nullptr, tid); }
  __syncthreads();
  eval_f(zl, h1l, h2l, kkl[5], nullptr, W0T, W1T, W2T, b0, b1, b2, tid);
  __syncthreads();

  // y_new -> zl (kept for err/scale) and ybuf[cur^1]
  { const float c[6] = {B1f, B2f, B3f, B4f, B5f, B6f};
    combine<6>(zl, yl, h, c, kkl, ybuf + (size_t)(st.cur^1)*BD + row0*Dn, tid); }
  __syncthreads();
  // k7 = f(y_new); also store to kbuf[cur^1] (becomes k1 on accept: FSAL)
  eval_f(zl, h1l, h2l, kkl[6], kbuf + (size_t)(st.cur^1)*BD + row0*Dn,
         W0T, W1T, W2T, b0, b1, b2, tid);
  __syncthreads();

  // error partial sums
  float local = 0.f;
  for (int e = tid; e < RPB*Dn; e += NTHR) {
    float a = E1f * kkl[0][e];
    a = fmaf(E2f, kkl[1][e], a);
    a = fmaf(E3f, kkl[2][e], a);
    a = fmaf(E4f, kkl[3][e], a);
    a = fmaf(E5f, kkl[4][e], a);
    a = fmaf(E6f, kkl[5][e], a);
    a = fmaf(E7f, kkl[6][e], a);
    const float ev = h * a;
    const float sc = fmaf(1e-3f, fmaxf(fabsf(yl[e]), fabsf(zl[e])), 1e-6f);
    const float q = ev / sc;
    local = fmaf(q, q, local);
  }
#pragma unroll
  for (int off = 32; off > 0; off >>= 1) local += __shfl_down(local, off);
  if ((tid & 63) == 0) wred[tid >> 6] = local;
  __syncthreads();
  if (tid == 0)
    atomicAdd(&slots[s], (double)(wred[0] + wred[1] + wred[2] + wred[3]));
}

extern "C" void kernel_launch(void* const* d_in, const int* in_sizes, int n_in,
                              void* d_out, int out_size, void* d_ws, size_t ws_size,
                              hipStream_t stream) {
  (void)in_sizes; (void)n_in; (void)out_size; (void)ws_size;
  const float* ts = (const float*)d_in[0];
  const float* y0 = (const float*)d_in[1];
  const float* W0 = (const float*)d_in[2];
  const float* b0 = (const float*)d_in[3];
  const float* W1 = (const float*)d_in[4];
  const float* b1 = (const float*)d_in[5];
  const float* W2 = (const float*)d_in[6];
  const float* b2 = (const float*)d_in[7];
  float* out = (float*)d_out;
  char* ws = (char*)d_ws;

  hipLaunchKernelGGL(ode_init, dim3((Tn*BD)/256), dim3(256), 0, stream,
                     ts, y0, W0, W1, W2, ws, out);
  for (int s = 0; s <= NSTEP; ++s)
    hipLaunchKernelGGL(ode_step, dim3(NBLK), dim3(NTHR), 0, stream,
                       s, ts, b0, b1, b2, ws, out);
}

// Round 2
// 940.906 us; speedup vs baseline: 2.9913x; 2.9913x over previous
//
#include <hip/hip_runtime.h>
#include <math.h>

#define DEVFN static __device__ __forceinline__

constexpr int Bn = 1024, Dn = 128, Wn = 512, Tn = 8;
constexpr int NSTEP = 48;
constexpr int RPB = 4;            // batch rows per block
constexpr int NBLK = Bn / RPB;    // 256 blocks = 1 per CU
constexpr int NTHR = 1024;        // 16 waves per CU
constexpr int BD = Bn * Dn;

// workspace byte offsets
constexpr size_t OFF_SLOTS = 0;                            // 48 doubles
constexpr size_t OFF_STATE = 512;                          // 2 x 64B state slots
constexpr size_t OFF_W0T   = 1024;                         // [Dn][Wn] f32
constexpr size_t OFF_W1T   = OFF_W0T + (size_t)Dn*Wn*4;    // [Wn][Wn] f32
constexpr size_t OFF_W2T   = OFF_W1T + (size_t)Wn*Wn*4;    // [Wn][Dn] f32
constexpr size_t OFF_Y     = OFF_W2T + (size_t)Wn*Dn*4;    // 2 x [Bn][Dn] f32
constexpr size_t OFF_K     = OFF_Y   + (size_t)2*BD*4;     // 2 x [Bn][Dn] f32

struct OdeState { int si; int cur; float t; float dt; };

// Tsit5 tableau (float)
constexpr float A21f = 0.161f;
constexpr float A31f = -0.008480655492356989f, A32f = 0.335480655492357f;
constexpr float A41f = 2.8971530571054935f, A42f = -6.359448489975075f, A43f = 4.3622954328695815f;
constexpr float A51f = 5.325864828439257f, A52f = -11.748883564062828f, A53f = 7.4955393428898365f, A54f = -0.09249506636175525f;
constexpr float A61f = 5.86145544294642f, A62f = -12.92096931784711f, A63f = 8.159367898576159f, A64f = -0.071584973281401f, A65f = -0.028269050394068383f;
constexpr float B1f = 0.09646076681806523f, B2f = 0.01f, B3f = 0.4798896504144996f, B4f = 1.379008574103742f, B5f = -3.290069515436081f, B6f = 2.324710524099774f;
constexpr float E1f = -0.00178001105222577714f, E2f = -0.0008164344596567469f, E3f = 0.007880878010261995f, E4f = -0.1447110071732629f, E5f = 0.5823571654525552f, E6f = -0.45808210592918697f, E7f = 0.015151515151515152f;

DEVFN float softplusf(float x) {
  // jax.nn.softplus == max(x,0) + log1p(exp(-|x|))
  return fmaxf(x, 0.f) + log1pf(expf(-fabsf(x)));
}

// One dense layer for this block's 4 rows, K-split across the 1024 threads.
// zl: [4][K] activations in LDS (wave-uniform broadcast reads).
// WT: [K][O] transposed weights in global (L2-resident), float4 loads.
// pl: [KSPL][4][O] f32 LDS partial buffer (16384 floats, shared/reused).
// outl: [4][O] LDS output; ACT -> softplus; outg: optional global mirror.
template<int K, int O, bool ACT, bool GOUT>
DEVFN void dense_layer(const float* __restrict__ zl, const float* __restrict__ WT,
                       const float* __restrict__ bias, float* __restrict__ pl,
                       float* __restrict__ outl, float* __restrict__ outg, int tid)
{
  constexpr int CG   = O / 4;          // col-groups (4 cols per thread)
  constexpr int KSPL = NTHR / CG;      // K-split factor
  constexpr int KL   = K / KSPL;       // K per thread
  static_assert(CG * KSPL == NTHR, "mapping");
  static_assert(KSPL * KL == K, "ksplit");

  const int kg = tid / CG;
  const int cg = tid % CG;
  const int oc = cg * 4;
  const int i0 = kg * KL;

  float acc[4][4];
#pragma unroll
  for (int r = 0; r < 4; ++r)
#pragma unroll
    for (int c = 0; c < 4; ++c) acc[r][c] = 0.f;

#pragma unroll 2
  for (int i = i0; i < i0 + KL; i += 4) {
    float zv[4][4];
#pragma unroll
    for (int r = 0; r < 4; ++r) {
      const float4 zt = *(const float4*)&zl[r*K + i];
      zv[r][0] = zt.x; zv[r][1] = zt.y; zv[r][2] = zt.z; zv[r][3] = zt.w;
    }
#pragma unroll
    for (int ii = 0; ii < 4; ++ii) {
      const float4 w = *(const float4*)&WT[(size_t)(i + ii)*O + oc];
#pragma unroll
      for (int r = 0; r < 4; ++r) {
        acc[r][0] = fmaf(zv[r][ii], w.x, acc[r][0]);
        acc[r][1] = fmaf(zv[r][ii], w.y, acc[r][1]);
        acc[r][2] = fmaf(zv[r][ii], w.z, acc[r][2]);
        acc[r][3] = fmaf(zv[r][ii], w.w, acc[r][3]);
      }
    }
  }
  // partials -> LDS
#pragma unroll
  for (int r = 0; r < 4; ++r) {
    float4 v; v.x = acc[r][0]; v.y = acc[r][1]; v.z = acc[r][2]; v.w = acc[r][3];
    *(float4*)&pl[(size_t)(kg*4 + r)*O + oc] = v;
  }
  __syncthreads();
  // reduce K-groups, bias, activation
  for (int e = tid; e < 4*O; e += NTHR) {
    const int r = e / O, c = e % O;
    float s = 0.f;
#pragma unroll
    for (int k2 = 0; k2 < KSPL; ++k2) s += pl[(size_t)(k2*4 + r)*O + c];
    s += bias[c];
    if (ACT) s = softplusf(s);
    outl[r*O + c] = s;
    if (GOUT) outg[e] = s;
  }
  __syncthreads();
}

DEVFN void eval_f(const float* __restrict__ zl, float* __restrict__ h1l,
                  float* __restrict__ h2l, float* __restrict__ pl,
                  float* __restrict__ kout, float* __restrict__ kglob,
                  const float* __restrict__ W0T, const float* __restrict__ W1T,
                  const float* __restrict__ W2T,
                  const float* __restrict__ b0, const float* __restrict__ b1,
                  const float* __restrict__ b2, int tid)
{
  dense_layer<Dn, Wn, true,  false>(zl,  W0T, b0, pl, h1l, nullptr, tid);
  dense_layer<Wn, Wn, true,  false>(h1l, W1T, b1, pl, h2l, nullptr, tid);
  if (kglob) dense_layer<Wn, Dn, false, true >(h2l, W2T, b2, pl, kout, kglob, tid);
  else       dense_layer<Wn, Dn, false, false>(h2l, W2T, b2, pl, kout, nullptr, tid);
}

template<int N>
DEVFN void combine(float* __restrict__ zl, const float* __restrict__ yl, float h,
                   const float* c, const float (*kkl)[RPB*Dn],
                   float* __restrict__ yglob, int tid)
{
  for (int e = tid; e < RPB*Dn; e += NTHR) {
    float a = c[0] * kkl[0][e];
#pragma unroll
    for (int l = 1; l < N; ++l) a = fmaf(c[l], kkl[l][e], a);
    const float v = fmaf(h, a, yl[e]);
    zl[e] = v;
    if (yglob) yglob[e] = v;
  }
}

__global__ __launch_bounds__(256) void ode_init(
    const float* __restrict__ ts, const float* __restrict__ y0,
    const float* __restrict__ W0, const float* __restrict__ W1,
    const float* __restrict__ W2, char* __restrict__ ws, float* __restrict__ out)
{
  const int idx = blockIdx.x * blockDim.x + threadIdx.x;
  float* W0T = (float*)(ws + OFF_W0T);
  float* W1T = (float*)(ws + OFF_W1T);
  float* W2T = (float*)(ws + OFF_W2T);
  float* y0b = (float*)(ws + OFF_Y);
  double* slots = (double*)(ws + OFF_SLOTS);

  if (idx < Tn*BD) out[idx] = (idx < BD) ? y0[idx] : 0.f;  // ys[0]=y0, rest zero
  if (idx < BD) y0b[idx] = y0[idx];
  if (idx < Dn*Wn) { const int i = idx >> 9, o = idx & (Wn-1); W0T[idx] = W0[o*Dn + i]; }
  if (idx < Wn*Wn) { const int i = idx >> 9, o = idx & (Wn-1); W1T[idx] = W1[o*Wn + i]; }
  if (idx < Wn*Dn) { const int i = idx >> 7, o = idx & (Dn-1); W2T[idx] = W2[o*Wn + i]; }
  if (idx < NSTEP) slots[idx] = 0.0;
  if (idx == 0) {
    OdeState s0; s0.si = 1; s0.cur = 0; s0.t = 0.f; s0.dt = ts[1] - ts[0];
    *(OdeState*)(ws + OFF_STATE)      = s0;
    *(OdeState*)(ws + OFF_STATE + 64) = s0;
  }
}

// Kernel s: phase B of step s-1 (finalize from reduced enorm), then phase A of
// step s (stages via FSAL, error partial sums). s==NSTEP is finalize-only.
__global__ __launch_bounds__(NTHR) void ode_step(
    int s, const float* __restrict__ ts,
    const float* __restrict__ b0, const float* __restrict__ b1,
    const float* __restrict__ b2,
    char* __restrict__ ws, float* __restrict__ out)
{
  const float* W0T = (const float*)(ws + OFF_W0T);
  const float* W1T = (const float*)(ws + OFF_W1T);
  const float* W2T = (const float*)(ws + OFF_W2T);
  float* ybuf = (float*)(ws + OFF_Y);
  float* kbuf = (float*)(ws + OFF_K);
  double* slots = (double*)(ws + OFF_SLOTS);

  __shared__ __align__(16) float zl[RPB*Dn];
  __shared__ __align__(16) float yl[RPB*Dn];
  __shared__ __align__(16) float h1l[RPB*Wn];
  __shared__ __align__(16) float h2l[RPB*Wn];
  __shared__ __align__(16) float pl[16384];        // 64 KB K-split partials
  __shared__ __align__(16) float kkl[7][RPB*Dn];
  __shared__ float wred[NTHR/64];

  const int tid  = threadIdx.x;
  const int row0 = blockIdx.x * RPB;

  OdeState st = *(const OdeState*)(ws + OFF_STATE + 64*(s & 1));

  if (s > 0) {
    // ---- phase B of step s-1: every block recomputes identically ----
    const bool donep = st.si >= Tn;
    const int sic = min(st.si, Tn - 1);
    const float tns = ts[sic];
    const float h = donep ? 0.f : fmaxf(fminf(st.dt, tns - st.t), 0.f);
    const float enorm = (float)sqrt(slots[s-1] / (double)BD);
    const bool accept = (enorm <= 1.f) && !donep;
    const float tnew = st.t + h;
    const bool hit = accept && (tnew >= tns - 1e-6f);
    if (accept) { st.cur ^= 1; st.t = tnew; }
    if (hit) {
      const float* yn = ybuf + (size_t)st.cur*BD + row0*Dn;
      float* op = out + (size_t)sic*BD + row0*Dn;
      for (int e = tid; e < RPB*Dn; e += NTHR) op[e] = yn[e];
      st.si += 1;
    }
    if (!donep) {
      const float safe_e = (enorm > 0.f) ? enorm : 1.f;
      const float factor = (enorm > 0.f)
          ? fminf(fmaxf(0.9f * powf(safe_e, -0.2f), 0.2f), 10.f) : 10.f;
      st.dt *= factor;
    }
    if (blockIdx.x == 0 && tid == 0)
      *(OdeState*)(ws + OFF_STATE + 64*((s+1) & 1)) = st;   // publish S_s
  }

  if (st.si >= Tn || s >= NSTEP) return;   // done (or finalize-only launch)

  // ---- phase A of step s ----
  const int sic = min(st.si, Tn - 1);
  const float tns = ts[sic];
  const float h = fmaxf(fminf(st.dt, tns - st.t), 0.f);

  const float* yg = ybuf + (size_t)st.cur*BD + row0*Dn;
  for (int e = tid; e < RPB*Dn; e += NTHR) yl[e] = yg[e];

  if (s == 0) {                 // bootstrap k1 = f(y0)
    for (int e = tid; e < RPB*Dn; e += NTHR) zl[e] = yg[e];
    __syncthreads();
    eval_f(zl, h1l, h2l, pl, kkl[0], kbuf + (size_t)st.cur*BD + row0*Dn,
           W0T, W1T, W2T, b0, b1, b2, tid);
  } else {                      // FSAL: k1 already in kbuf[cur]
    const float* kg = kbuf + (size_t)st.cur*BD + row0*Dn;
    for (int e = tid; e < RPB*Dn; e += NTHR) kkl[0][e] = kg[e];
    __syncthreads();
  }

  { const float c[1] = {A21f};
    combine<1>(zl, yl, h, c, kkl, nullptr, tid); }
  __syncthreads();
  eval_f(zl, h1l, h2l, pl, kkl[1], nullptr, W0T, W1T, W2T, b0, b1, b2, tid);

  { const float c[2] = {A31f, A32f};
    combine<2>(zl, yl, h, c, kkl, nullptr, tid); }
  __syncthreads();
  eval_f(zl, h1l, h2l, pl, kkl[2], nullptr, W0T, W1T, W2T, b0, b1, b2, tid);

  { const float c[3] = {A41f, A42f, A43f};
    combine<3>(zl, yl, h, c, kkl, nullptr, tid); }
  __syncthreads();
  eval_f(zl, h1l, h2l, pl, kkl[3], nullptr, W0T, W1T, W2T, b0, b1, b2, tid);

  { const float c[4] = {A51f, A52f, A53f, A54f};
    combine<4>(zl, yl, h, c, kkl, nullptr, tid); }
  __syncthreads();
  eval_f(zl, h1l, h2l, pl, kkl[4], nullptr, W0T, W1T, W2T, b0, b1, b2, tid);

  { const float c[5] = {A61f, A62f, A63f, A64f, A65f};
    combine<5>(zl, yl, h, c, kkl, nullptr, tid); }
  __syncthreads();
  eval_f(zl, h1l, h2l, pl, kkl[5], nullptr, W0T, W1T, W2T, b0, b1, b2, tid);

  // y_new -> zl (kept for err/scale) and ybuf[cur^1]
  { const float c[6] = {B1f, B2f, B3f, B4f, B5f, B6f};
    combine<6>(zl, yl, h, c, kkl, ybuf + (size_t)(st.cur^1)*BD + row0*Dn, tid); }
  __syncthreads();
  // k7 = f(y_new); also store to kbuf[cur^1] (becomes k1 on accept: FSAL)
  eval_f(zl, h1l, h2l, pl, kkl[6], kbuf + (size_t)(st.cur^1)*BD + row0*Dn,
         W0T, W1T, W2T, b0, b1, b2, tid);

  // error partial sums (512 elements; threads >= 512 contribute 0)
  float local = 0.f;
  for (int e = tid; e < RPB*Dn; e += NTHR) {
    float a = E1f * kkl[0][e];
    a = fmaf(E2f, kkl[1][e], a);
    a = fmaf(E3f, kkl[2][e], a);
    a = fmaf(E4f, kkl[3][e], a);
    a = fmaf(E5f, kkl[4][e], a);
    a = fmaf(E6f, kkl[5][e], a);
    a = fmaf(E7f, kkl[6][e], a);
    const float ev = h * a;
    const float sc = fmaf(1e-3f, fmaxf(fabsf(yl[e]), fabsf(zl[e])), 1e-6f);
    const float q = ev / sc;
    local = fmaf(q, q, local);
  }
#pragma unroll
  for (int off = 32; off > 0; off >>= 1) local += __shfl_down(local, off);
  if ((tid & 63) == 0) wred[tid >> 6] = local;
  __syncthreads();
  if (tid == 0) {
    float tot = 0.f;
#pragma unroll
    for (int w = 0; w < NTHR/64; ++w) tot += wred[w];
    atomicAdd(&slots[s], (double)tot);
  }
}

extern "C" void kernel_launch(void* const* d_in, const int* in_sizes, int n_in,
                              void* d_out, int out_size, void* d_ws, size_t ws_size,
                              hipStream_t stream) {
  (void)in_sizes; (void)n_in; (void)out_size; (void)ws_size;
  const float* ts = (const float*)d_in[0];
  const float* y0 = (const float*)d_in[1];
  const float* W0 = (const float*)d_in[2];
  const float* b0 = (const float*)d_in[3];
  const float* W1 = (const float*)d_in[4];
  const float* b1 = (const float*)d_in[5];
  const float* W2 = (const float*)d_in[6];
  const float* b2 = (const float*)d_in[7];
  float* out = (float*)d_out;
  char* ws = (char*)d_ws;

  hipLaunchKernelGGL(ode_init, dim3((Tn*BD)/256), dim3(256), 0, stream,
                     ts, y0, W0, W1, W2, ws, out);
  for (int s = 0; s <= NSTEP; ++s)
    hipLaunchKernelGGL(ode_step, dim3(NBLK), dim3(NTHR), 0, stream,
                       s, ts, b0, b1, b2, ws, out);
}